// Round 1
// baseline (272.267 us; speedup 1.0000x reference)
//
#include <hip/hip_runtime.h>
#include <hip/hip_bf16.h>
#include <stdint.h>

#define NB   32
#define CIN  256
#define COUT 256
#define HH   56
#define WW   56
#define HW   3136
#define NEXP 3
#define KTOT 2304          // 9 * 256
#define XP   58
#define XPP  3364          // 58*58

#define BM 128
#define BN 128
#define NSTEP 72           // 2304 / 32

typedef __attribute__((ext_vector_type(8))) __bf16 bf16x8;
typedef __attribute__((ext_vector_type(4))) float  f32x4;

// workspace layout (bytes)
#define OFF_RW     0
#define OFF_POOLED 1024
#define OFF_CWT    (1024 + 32*256*16*4)            // 525,312
#define CWT_BYTES  ((size_t)NB*COUT*KTOT*2)        // 37,748,736
#define OFF_XPAD   (OFF_CWT + CWT_BYTES)           // 38,274,048
#define XPAD_BYTES ((size_t)NB*XPP*CIN*2)          // 55,115,776

// ---------------- pooling: x[b,c,56,56] -> pooled[b,c,16] (block means) -----
__global__ __launch_bounds__(256) void k_pool(const float* __restrict__ x,
                                              float* __restrict__ pooled) {
    int b = blockIdx.x, c = blockIdx.y;
    const float* xb = x + ((size_t)(b * CIN + c)) * HW;
    __shared__ float lds[4][56];
    int t = threadIdx.x;
    if (t < 224) {
        int xc = t % 56, yg = t / 56;          // yg = sy block
        const float* p = xb + (yg * 14) * WW + xc;
        float s = 0.f;
        #pragma unroll
        for (int r = 0; r < 14; ++r) s += p[r * WW];
        lds[yg][xc] = s;
    }
    __syncthreads();
    if (t < 16) {
        int sy = t >> 2, sx = t & 3;
        float s = 0.f;
        #pragma unroll
        for (int j = 0; j < 14; ++j) s += lds[sy][sx * 14 + j];
        pooled[(((size_t)b * CIN + c) << 4) + t] = s * (1.f / 196.f);
    }
}

// ---------------- routing: pooled -> rw[b,3] --------------------------------
__global__ __launch_bounds__(256) void k_route(const float* __restrict__ pooled,
                                               const float* __restrict__ rcw,
                                               const float* __restrict__ rcb,
                                               const float* __restrict__ fcw,
                                               const float* __restrict__ fcb,
                                               float* __restrict__ rw) {
    int b = blockIdx.x;
    int t = threadIdx.x;
    int r = t >> 4, ij = t & 15;
    __shared__ float rbuf[256];
    const float* pb = pooled + (size_t)b * CIN * 16;
    float acc = rcb[r];
    for (int c = 0; c < CIN; ++c)
        acc += pb[c * 16 + ij] * rcw[r * CIN + c];
    rbuf[t] = fmaxf(acc, 0.f);                 // flat idx = r*16 + (i*4+j)
    __syncthreads();
    if (t < NEXP) {
        float a = fcb[t];
        for (int f = 0; f < 256; ++f) a += rbuf[f] * fcw[t * 256 + f];
        a = fmaxf(a, 0.f);
        rw[b * NEXP + t] = 1.f / (1.f + expf(-a));
    }
}

// ---------------- weight mixing: cwt[b][o][kk*256+i] bf16 -------------------
__global__ __launch_bounds__(256) void k_mixw(const float* __restrict__ we,
                                              const float* __restrict__ rw,
                                              __bf16* __restrict__ cwt) {
    int o = blockIdx.x;
    int i = threadIdx.x;
    float wv[3][9];
    #pragma unroll
    for (int e = 0; e < 3; ++e) {
        const float* p = we + (((size_t)e * COUT + o) * CIN + i) * 9;
        #pragma unroll
        for (int k = 0; k < 9; ++k) wv[e][k] = p[k];
    }
    for (int b = 0; b < NB; ++b) {
        float r0 = rw[b * 3 + 0], r1 = rw[b * 3 + 1], r2 = rw[b * 3 + 2];
        __bf16* op = cwt + ((size_t)(b * COUT + o)) * KTOT + i;
        #pragma unroll
        for (int k = 0; k < 9; ++k) {
            float v = r0 * wv[0][k] + r1 * wv[1][k] + r2 * wv[2][k];
            op[k * 256] = (__bf16)v;
        }
    }
}

// ---------------- x -> xpad[b][yy][xx][c] bf16 (channels-last, padded) ------
__global__ __launch_bounds__(256) void k_xpad(const float* __restrict__ x,
                                              __bf16* __restrict__ xpad) {
    // grid: (49 ptile, 4 ctile, 32 b); tile = 64 spatial x 64 channels
    int pt = blockIdx.x, ct = blockIdx.y, b = blockIdx.z;
    int t = threadIdx.x;
    __shared__ __bf16 lds[64][66];             // pad 66 to break conflicts
    int pl = t & 63;
    int cb = t >> 6;
    const float* xb = x + ((size_t)(b * CIN + ct * 64)) * HW + pt * 64;
    #pragma unroll
    for (int ic = 0; ic < 16; ++ic) {
        int cl = ic * 4 + cb;
        lds[cl][pl] = (__bf16)xb[(size_t)cl * HW + pl];
    }
    __syncthreads();
    #pragma unroll
    for (int iw = 0; iw < 2; ++iw) {
        int idx = iw * 256 + t;
        int p_l = idx >> 3, c8 = (idx & 7) * 8;
        int p = pt * 64 + p_l;
        int y = p / WW, xx = p - y * WW;
        union { __bf16 h[8]; uint4 u; } pk;
        #pragma unroll
        for (int j = 0; j < 8; ++j) pk.h[j] = lds[c8 + j][p_l];
        __bf16* dst = xpad + ((size_t)b * XPP + (y + 1) * XP + (xx + 1)) * CIN
                      + ct * 64 + c8;
        *(uint4*)dst = pk.u;
    }
}

// ---------------- implicit-GEMM conv ----------------------------------------
#define GL16(g, l) __builtin_amdgcn_global_load_lds( \
    (const __attribute__((address_space(1))) uint32_t*)(g), \
    (__attribute__((address_space(3))) uint32_t*)(l), 16, 0, 0)

__global__ __launch_bounds__(256) void k_conv(const __bf16* __restrict__ cwt,
                                              const __bf16* __restrict__ xpad,
                                              float* __restrict__ out) {
    __shared__ __attribute__((aligned(16))) __bf16 ldsA[2][BM * 32];
    __shared__ __attribute__((aligned(16))) __bf16 ldsB[2][BN * 32];

    // XCD-aware swizzle: 1600 blocks, 8 XCDs -> 200 logical blocks per XCD
    int flat = blockIdx.x;
    int logical = (flat & 7) * 200 + (flat >> 3);
    int b = logical / 50;
    int rem = logical - b * 50;
    int mtile = rem / 25;
    int ntile = rem - mtile * 25;

    int t = threadIdx.x;
    int lane = t & 63;
    int wv = t >> 6;

    // staging: chunk = 16B; thread covers chunk (wv*64+lane) and +256
    int ch = wv * 64 + lane;
    int rm = ch >> 2;                 // row within 0..63
    int kp = ch & 3;                  // 16B sub-chunk of the 64B k-row

    const char* aBase = (const char*)(cwt +
        ((size_t)(b * COUT + mtile * BM + rm)) * KTOT) + kp * 16;
    const char* aBase2 = aBase + (size_t)64 * KTOT * 2;

    int p0 = ntile * BN + rm;
    int p1 = p0 + 64;
    int pv0 = p0 < HW ? p0 : HW - 1;  // clamp; stores are masked
    int pv1 = p1 < HW ? p1 : HW - 1;
    int y0 = pv0 / WW, x0 = pv0 - y0 * WW;
    int y1 = pv1 / WW, x1 = pv1 - y1 * WW;
    const char* bBase0 = (const char*)(xpad +
        ((size_t)b * XPP + y0 * XP + x0) * CIN) + kp * 16;
    const char* bBase1 = (const char*)(xpad +
        ((size_t)b * XPP + y1 * XP + x1) * CIN) + kp * 16;

    char* ldsA0 = (char*)&ldsA[0][0] + wv * 1024;
    char* ldsB0 = (char*)&ldsB[0][0] + wv * 1024;

#define STAGE(buf, s) do { \
        int kk_ = (s) >> 3; \
        int ky_ = kk_ / 3, kx_ = kk_ - ky_ * 3; \
        int offA_ = (s) * 64; \
        int offB_ = ((ky_ * XP + kx_) * CIN + ((s) & 7) * 32) * 2; \
        GL16(aBase  + offA_, ldsA0 + (buf) * 8192); \
        GL16(aBase2 + offA_, ldsA0 + (buf) * 8192 + 4096); \
        GL16(bBase0 + offB_, ldsB0 + (buf) * 8192); \
        GL16(bBase1 + offB_, ldsB0 + (buf) * 8192 + 4096); \
    } while (0)

    int wm = (wv & 1) * 64;
    int wn = (wv >> 1) * 64;
    int fr = lane & 15;
    int kb = (lane >> 4) * 8;

    f32x4 acc[4][4];
    #pragma unroll
    for (int i = 0; i < 4; ++i)
        #pragma unroll
        for (int j = 0; j < 4; ++j)
            acc[i][j] = (f32x4){0.f, 0.f, 0.f, 0.f};

    STAGE(0, 0);
    for (int s = 0; s < NSTEP; ++s) {
        __syncthreads();
        if (s + 1 < NSTEP) STAGE((s + 1) & 1, s + 1);
        const __bf16* Ab = &ldsA[s & 1][0];
        const __bf16* Bb = &ldsB[s & 1][0];
        bf16x8 af[4], bfr[4];
        #pragma unroll
        for (int mf = 0; mf < 4; ++mf)
            af[mf] = *(const bf16x8*)(Ab + (wm + mf * 16 + fr) * 32 + kb);
        #pragma unroll
        for (int nf = 0; nf < 4; ++nf)
            bfr[nf] = *(const bf16x8*)(Bb + (wn + nf * 16 + fr) * 32 + kb);
        #pragma unroll
        for (int mf = 0; mf < 4; ++mf)
            #pragma unroll
            for (int nf = 0; nf < 4; ++nf)
                acc[mf][nf] = __builtin_amdgcn_mfma_f32_16x16x32_bf16(
                    af[mf], bfr[nf], acc[mf][nf], 0, 0, 0);
    }

    // epilogue: D col = lane&15, row = (lane>>4)*4 + reg
    float* ob = out + ((size_t)(b * COUT + mtile * BM + wm)) * HW;
    int colbase = ntile * BN + wn;
    int rb = (lane >> 4) * 4;
    #pragma unroll
    for (int nf = 0; nf < 4; ++nf) {
        int pc = colbase + nf * 16 + fr;
        if (pc < HW) {
            #pragma unroll
            for (int mf = 0; mf < 4; ++mf)
                #pragma unroll
                for (int r = 0; r < 4; ++r)
                    ob[(size_t)(mf * 16 + rb + r) * HW + pc] = acc[mf][nf][r];
        }
    }
#undef STAGE
}

// ---------------------------------------------------------------------------
extern "C" void kernel_launch(void* const* d_in, const int* in_sizes, int n_in,
                              void* d_out, int out_size, void* d_ws, size_t ws_size,
                              hipStream_t stream) {
    (void)in_sizes; (void)n_in; (void)out_size; (void)ws_size;
    const float* x   = (const float*)d_in[0];
    const float* we  = (const float*)d_in[1];
    const float* rcw = (const float*)d_in[2];
    const float* rcb = (const float*)d_in[3];
    const float* fcw = (const float*)d_in[4];
    const float* fcb = (const float*)d_in[5];
    float* out = (float*)d_out;

    char* ws = (char*)d_ws;
    float*  rw     = (float*)(ws + OFF_RW);
    float*  pooled = (float*)(ws + OFF_POOLED);
    __bf16* cwt    = (__bf16*)(ws + OFF_CWT);
    __bf16* xpad   = (__bf16*)(ws + OFF_XPAD);

    (void)hipMemsetAsync(xpad, 0, XPAD_BYTES, stream);   // zero borders
    k_pool<<<dim3(NB, CIN), 256, 0, stream>>>(x, pooled);
    k_route<<<NB, 256, 0, stream>>>(pooled, rcw, rcb, fcw, fcb, rw);
    k_mixw<<<COUT, 256, 0, stream>>>(we, rw, cwt);
    k_xpad<<<dim3(49, 4, NB), 256, 0, stream>>>(x, xpad);
    k_conv<<<1600, 256, 0, stream>>>(cwt, xpad, out);
}

// Round 4
// 245.686 us; speedup vs baseline: 1.1082x; 1.1082x over previous
//
#include <hip/hip_runtime.h>
#include <hip/hip_bf16.h>
#include <stdint.h>

#define NB   32
#define CIN  256
#define COUT 256
#define HH   56
#define WW   56
#define HW   3136
#define NEXP 3
#define KTOT 2304          // 9 * 256
#define XP   58
#define XPP  3364          // 58*58

#define BM 128
#define BN 128

typedef __attribute__((ext_vector_type(8))) __bf16 bf16x8;
typedef __attribute__((ext_vector_type(4))) float  f32x4;

// workspace layout (bytes)
#define OFF_RW     0
#define OFF_POOLED 1024
#define OFF_CWT    (1024 + 32*256*16*4)            // 525,312
#define CWT_BYTES  ((size_t)NB*COUT*KTOT*2)        // 37,748,736
#define OFF_XPAD   (OFF_CWT + CWT_BYTES)           // 38,274,048
#define XPAD_BYTES ((size_t)NB*XPP*CIN*2)          // 55,115,776

// ---------------- pooling: x[b,c,56,56] -> pooled[b,c,16] (block means) -----
__global__ __launch_bounds__(256) void k_pool(const float* __restrict__ x,
                                              float* __restrict__ pooled) {
    int b = blockIdx.x, c = blockIdx.y;
    const float* xb = x + ((size_t)(b * CIN + c)) * HW;
    __shared__ float lds[4][56];
    int t = threadIdx.x;
    if (t < 224) {
        int xc = t % 56, yg = t / 56;
        const float* p = xb + (yg * 14) * WW + xc;
        float s = 0.f;
        #pragma unroll
        for (int r = 0; r < 14; ++r) s += p[r * WW];
        lds[yg][xc] = s;
    }
    __syncthreads();
    if (t < 16) {
        int sy = t >> 2, sx = t & 3;
        float s = 0.f;
        #pragma unroll
        for (int j = 0; j < 14; ++j) s += lds[sy][sx * 14 + j];
        pooled[(((size_t)b * CIN + c) << 4) + t] = s * (1.f / 196.f);
    }
}

// ---------------- routing: pooled -> rw[b,3] --------------------------------
__global__ __launch_bounds__(256) void k_route(const float* __restrict__ pooled,
                                               const float* __restrict__ rcw,
                                               const float* __restrict__ rcb,
                                               const float* __restrict__ fcw,
                                               const float* __restrict__ fcb,
                                               float* __restrict__ rw) {
    int b = blockIdx.x;
    int t = threadIdx.x;
    int r = t >> 4, ij = t & 15;
    __shared__ float rbuf[256];
    const float* pb = pooled + (size_t)b * CIN * 16;
    float acc = rcb[r];
    for (int c = 0; c < CIN; ++c)
        acc += pb[c * 16 + ij] * rcw[r * CIN + c];
    rbuf[t] = fmaxf(acc, 0.f);
    __syncthreads();
    if (t < NEXP) {
        float a = fcb[t];
        for (int f = 0; f < 256; ++f) a += rbuf[f] * fcw[t * 256 + f];
        a = fmaxf(a, 0.f);
        rw[b * NEXP + t] = 1.f / (1.f + expf(-a));
    }
}

// ---------------- weight mixing: cwt[b][o][kk*256+i] bf16 -------------------
__global__ __launch_bounds__(256) void k_mixw(const float* __restrict__ we,
                                              const float* __restrict__ rw,
                                              __bf16* __restrict__ cwt) {
    int o = blockIdx.x;
    int i = threadIdx.x;
    float wv[3][9];
    #pragma unroll
    for (int e = 0; e < 3; ++e) {
        const float* p = we + (((size_t)e * COUT + o) * CIN + i) * 9;
        #pragma unroll
        for (int k = 0; k < 9; ++k) wv[e][k] = p[k];
    }
    for (int b = 0; b < NB; ++b) {
        float r0 = rw[b * 3 + 0], r1 = rw[b * 3 + 1], r2 = rw[b * 3 + 2];
        __bf16* op = cwt + ((size_t)(b * COUT + o)) * KTOT + i;
        #pragma unroll
        for (int k = 0; k < 9; ++k) {
            float v = r0 * wv[0][k] + r1 * wv[1][k] + r2 * wv[2][k];
            op[k * 256] = (__bf16)v;
        }
    }
}

// ---------------- zero only xpad borders (replaces 55MB memset) -------------
__global__ __launch_bounds__(256) void k_zborder(__bf16* __restrict__ xpad) {
    int b = blockIdx.x;
    // 228 border cells * 32 uint4-chunks (256ch * 2B = 512B each)
    for (int idx = threadIdx.x; idx < 228 * 32; idx += 256) {
        int pos = idx >> 5;
        int co = (idx & 31) * 8;          // channel offset (8 bf16 per 16B)
        int yy, xx;
        if (pos < 58)       { yy = 0;          xx = pos; }
        else if (pos < 116) { yy = 57;         xx = pos - 58; }
        else if (pos < 172) { yy = pos - 115;  xx = 0; }     // yy 1..56
        else                { yy = pos - 171;  xx = 57; }    // yy 1..56
        uint4 z = {0u, 0u, 0u, 0u};
        *(uint4*)(xpad + ((size_t)b * XPP + yy * XP + xx) * CIN + co) = z;
    }
}

// ---------------- x -> xpad[b][yy][xx][c] bf16 (channels-last, padded) ------
__global__ __launch_bounds__(256) void k_xpad(const float* __restrict__ x,
                                              __bf16* __restrict__ xpad) {
    int pt = blockIdx.x, ct = blockIdx.y, b = blockIdx.z;
    int t = threadIdx.x;
    __shared__ __bf16 lds[64][66];
    int pl = t & 63;
    int cb = t >> 6;
    const float* xb = x + ((size_t)(b * CIN + ct * 64)) * HW + pt * 64;
    #pragma unroll
    for (int ic = 0; ic < 16; ++ic) {
        int cl = ic * 4 + cb;
        lds[cl][pl] = (__bf16)xb[(size_t)cl * HW + pl];
    }
    __syncthreads();
    #pragma unroll
    for (int iw = 0; iw < 2; ++iw) {
        int idx = iw * 256 + t;
        int p_l = idx >> 3, c8 = (idx & 7) * 8;
        int p = pt * 64 + p_l;
        int y = p / WW, xx = p - y * WW;
        union { __bf16 h[8]; uint4 u; } pk;
        #pragma unroll
        for (int j = 0; j < 8; ++j) pk.h[j] = lds[c8 + j][p_l];
        __bf16* dst = xpad + ((size_t)b * XPP + (y + 1) * XP + (xx + 1)) * CIN
                      + ct * 64 + c8;
        *(uint4*)dst = pk.u;
    }
}

// ---------------- implicit-GEMM conv ----------------------------------------
#define GL16(g, l) __builtin_amdgcn_global_load_lds( \
    (const __attribute__((address_space(1))) uint32_t*)(g), \
    (__attribute__((address_space(3))) uint32_t*)(l), 16, 0, 0)

__global__ __launch_bounds__(256) void k_conv(const __bf16* __restrict__ cwt,
                                              const __bf16* __restrict__ xpad,
                                              float* __restrict__ out) {
    __shared__ __attribute__((aligned(16))) __bf16 ldsA[2][BM * 32];
    __shared__ __attribute__((aligned(16))) __bf16 ldsB[2][BN * 32];

    // XCD-aware swizzle: 1600 blocks, 8 XCDs -> 200 logical per XCD
    int flat = blockIdx.x;
    int logical = (flat & 7) * 200 + (flat >> 3);
    int b = logical / 50;
    int rem = logical - b * 50;
    int mtile = rem / 25;
    int ntile = rem - mtile * 25;

    int t = threadIdx.x;
    int lane = t & 63;
    int wv = t >> 6;

    int ch = wv * 64 + lane;
    int rm = ch >> 2;                 // row 0..63
    int kp = ch & 3;                  // 16B sub-chunk of 64B k-row

    const char* aP = (const char*)(cwt +
        ((size_t)(b * COUT + mtile * BM + rm)) * KTOT) + kp * 16;
    const char* aP2 = aP + (size_t)64 * KTOT * 2;

    int p0 = ntile * BN + rm;
    int p1v = p0 + 64;
    int pv0 = p0 < HW ? p0 : HW - 1;  // clamp; stores are masked
    int pv1 = p1v < HW ? p1v : HW - 1;
    int y0 = pv0 / WW, x0 = pv0 - y0 * WW;
    int y1 = pv1 / WW, x1 = pv1 - y1 * WW;
    const char* bP0 = (const char*)(xpad +
        ((size_t)b * XPP + y0 * XP + x0) * CIN) + kp * 16;
    const char* bP1 = (const char*)(xpad +
        ((size_t)b * XPP + y1 * XP + x1) * CIN) + kp * 16;

    char* ldsA0 = (char*)&ldsA[0][0] + wv * 1024;
    char* ldsB0 = (char*)&ldsB[0][0] + wv * 1024;

    int wm = (wv & 1) * 64;
    int wn = (wv >> 1) * 64;
    int fr = lane & 15;
    int kb = (lane >> 4) * 8;

    // loop-invariant LDS read bases; per-step offsets are immediates
    const char* ArdBase = (const char*)&ldsA[0][0] + (wm + fr) * 64 + kb * 2;
    const char* BrdBase = (const char*)&ldsB[0][0] + (wn + fr) * 64 + kb * 2;

    f32x4 acc[4][4];
    #pragma unroll
    for (int i = 0; i < 4; ++i)
        #pragma unroll
        for (int j = 0; j < 4; ++j)
            acc[i][j] = (f32x4){0.f, 0.f, 0.f, 0.f};

    // prestage step 0 into buffer 0
    GL16(aP, ldsA0);
    GL16(aP2, ldsA0 + 4096);
    GL16(bP0, ldsB0);
    GL16(bP1, ldsB0 + 4096);

    for (int kk = 0; kk < 9; ++kk) {
        int kr = kk - (kk / 3) * 3;               // kk % 3
        int dB = (kr == 2) ? 28672 : 512;         // B-base delta to next tap
        #pragma unroll
        for (int j = 0; j < 8; ++j) {
            __syncthreads();
            const int pn = ((j + 1) & 1) * 8192;  // next buffer (literal)
            if (j < 7) {                          // compile-time branch
                GL16(aP  + (j + 1) * 64, ldsA0 + pn);
                GL16(aP2 + (j + 1) * 64, ldsA0 + pn + 4096);
                GL16(bP0 + (j + 1) * 64, ldsB0 + pn);
                GL16(bP1 + (j + 1) * 64, ldsB0 + pn + 4096);
            } else if (kk < 8) {                  // uniform runtime branch
                GL16(aP  + 512, ldsA0 + pn);
                GL16(aP2 + 512, ldsA0 + pn + 4096);
                GL16(bP0 + dB, ldsB0 + pn);
                GL16(bP1 + dB, ldsB0 + pn + 4096);
            }
            const int pc = (j & 1) * 8192;        // current buffer (literal)
            bf16x8 af[4], bfr[4];
            #pragma unroll
            for (int mf = 0; mf < 4; ++mf)
                af[mf] = *(const bf16x8*)(ArdBase + pc + mf * 1024);
            #pragma unroll
            for (int nf = 0; nf < 4; ++nf)
                bfr[nf] = *(const bf16x8*)(BrdBase + pc + nf * 1024);
            #pragma unroll
            for (int mf = 0; mf < 4; ++mf)
                #pragma unroll
                for (int nf = 0; nf < 4; ++nf)
                    acc[mf][nf] = __builtin_amdgcn_mfma_f32_16x16x32_bf16(
                        af[mf], bfr[nf], acc[mf][nf], 0, 0, 0);
        }
        aP += 512; aP2 += 512; bP0 += dB; bP1 += dB;
    }

    // epilogue: D col = lane&15, row = (lane>>4)*4 + reg
    float* ob = out + ((size_t)(b * COUT + mtile * BM + wm)) * HW;
    int colbase = ntile * BN + wn;
    int rb = (lane >> 4) * 4;
    #pragma unroll
    for (int nf = 0; nf < 4; ++nf) {
        int pc = colbase + nf * 16 + fr;
        if (pc < HW) {
            #pragma unroll
            for (int mf = 0; mf < 4; ++mf)
                #pragma unroll
                for (int r = 0; r < 4; ++r)
                    ob[(size_t)(mf * 16 + rb + r) * HW + pc] = acc[mf][nf][r];
        }
    }
}

// ---------------------------------------------------------------------------
extern "C" void kernel_launch(void* const* d_in, const int* in_sizes, int n_in,
                              void* d_out, int out_size, void* d_ws, size_t ws_size,
                              hipStream_t stream) {
    (void)in_sizes; (void)n_in; (void)out_size; (void)ws_size;
    const float* x   = (const float*)d_in[0];
    const float* we  = (const float*)d_in[1];
    const float* rcw = (const float*)d_in[2];
    const float* rcb = (const float*)d_in[3];
    const float* fcw = (const float*)d_in[4];
    const float* fcb = (const float*)d_in[5];
    float* out = (float*)d_out;

    char* ws = (char*)d_ws;
    float*  rw     = (float*)(ws + OFF_RW);
    float*  pooled = (float*)(ws + OFF_POOLED);
    __bf16* cwt    = (__bf16*)(ws + OFF_CWT);
    __bf16* xpad   = (__bf16*)(ws + OFF_XPAD);

    k_zborder<<<NB, 256, 0, stream>>>(xpad);
    k_pool<<<dim3(NB, CIN), 256, 0, stream>>>(x, pooled);
    k_route<<<NB, 256, 0, stream>>>(pooled, rcw, rcb, fcw, fcb, rw);
    k_mixw<<<COUT, 256, 0, stream>>>(we, rw, cwt);
    k_xpad<<<dim3(49, 4, NB), 256, 0, stream>>>(x, xpad);
    k_conv<<<1600, 256, 0, stream>>>(cwt, xpad, out);
}

// Round 6
// 202.663 us; speedup vs baseline: 1.3435x; 1.2123x over previous
//
#include <hip/hip_runtime.h>
#include <hip/hip_bf16.h>
#include <stdint.h>

#define NB   32
#define CIN  256
#define COUT 256
#define WW   56
#define HW   3136
#define NEXP 3
#define KTOT 2304          // 9 * 256
#define XP   58
#define XPP  3364          // 58*58
#define NKT  36            // K-tiles of 64

typedef __attribute__((ext_vector_type(8))) __bf16 bf16x8;
typedef __attribute__((ext_vector_type(4))) float  f32x4;

// workspace layout (bytes)
#define OFF_RW     0
#define OFF_POOLED 1024
#define OFF_CWT    (1024 + 32*256*16*4)
#define CWT_BYTES  ((size_t)NB*COUT*KTOT*2)
#define OFF_XPAD   (OFF_CWT + CWT_BYTES)

// ---------------- pooling ---------------------------------------------------
__global__ __launch_bounds__(256) void k_pool(const float* __restrict__ x,
                                              float* __restrict__ pooled) {
    int b = blockIdx.x, c = blockIdx.y;
    const float* xb = x + ((size_t)(b * CIN + c)) * HW;
    __shared__ float lds[4][56];
    int t = threadIdx.x;
    if (t < 224) {
        int xc = t % 56, yg = t / 56;
        const float* p = xb + (yg * 14) * WW + xc;
        float s = 0.f;
        #pragma unroll
        for (int r = 0; r < 14; ++r) s += p[r * WW];
        lds[yg][xc] = s;
    }
    __syncthreads();
    if (t < 16) {
        int sy = t >> 2, sx = t & 3;
        float s = 0.f;
        #pragma unroll
        for (int j = 0; j < 14; ++j) s += lds[sy][sx * 14 + j];
        pooled[(((size_t)b * CIN + c) << 4) + t] = s * (1.f / 196.f);
    }
}

// ---------------- routing ---------------------------------------------------
__global__ __launch_bounds__(256) void k_route(const float* __restrict__ pooled,
                                               const float* __restrict__ rcw,
                                               const float* __restrict__ rcb,
                                               const float* __restrict__ fcw,
                                               const float* __restrict__ fcb,
                                               float* __restrict__ rw) {
    int b = blockIdx.x;
    int t = threadIdx.x;
    int r = t >> 4, ij = t & 15;
    __shared__ float rbuf[256];
    const float* pb = pooled + (size_t)b * CIN * 16;
    float acc = rcb[r];
    for (int c = 0; c < CIN; ++c)
        acc += pb[c * 16 + ij] * rcw[r * CIN + c];
    rbuf[t] = fmaxf(acc, 0.f);
    __syncthreads();
    if (t < NEXP) {
        float a = fcb[t];
        for (int f = 0; f < 256; ++f) a += rbuf[f] * fcw[t * 256 + f];
        a = fmaxf(a, 0.f);
        rw[b * NEXP + t] = 1.f / (1.f + expf(-a));
    }
}

// ---------------- weight mixing ---------------------------------------------
__global__ __launch_bounds__(256) void k_mixw(const float* __restrict__ we,
                                              const float* __restrict__ rw,
                                              __bf16* __restrict__ cwt) {
    int o = blockIdx.x;
    int i = threadIdx.x;
    float wv[3][9];
    #pragma unroll
    for (int e = 0; e < 3; ++e) {
        const float* p = we + (((size_t)e * COUT + o) * CIN + i) * 9;
        #pragma unroll
        for (int k = 0; k < 9; ++k) wv[e][k] = p[k];
    }
    for (int b = 0; b < NB; ++b) {
        float r0 = rw[b * 3 + 0], r1 = rw[b * 3 + 1], r2 = rw[b * 3 + 2];
        __bf16* op = cwt + ((size_t)(b * COUT + o)) * KTOT + i;
        #pragma unroll
        for (int k = 0; k < 9; ++k) {
            float v = r0 * wv[0][k] + r1 * wv[1][k] + r2 * wv[2][k];
            op[k * 256] = (__bf16)v;
        }
    }
}

// ---------------- zero xpad borders -----------------------------------------
__global__ __launch_bounds__(256) void k_zborder(__bf16* __restrict__ xpad) {
    int b = blockIdx.x;
    for (int idx = threadIdx.x; idx < 228 * 32; idx += 256) {
        int pos = idx >> 5;
        int co = (idx & 31) * 8;
        int yy, xx;
        if (pos < 58)       { yy = 0;          xx = pos; }
        else if (pos < 116) { yy = 57;         xx = pos - 58; }
        else if (pos < 172) { yy = pos - 115;  xx = 0; }
        else                { yy = pos - 171;  xx = 57; }
        uint4 z = {0u, 0u, 0u, 0u};
        *(uint4*)(xpad + ((size_t)b * XPP + yy * XP + xx) * CIN + co) = z;
    }
}

// ---------------- x -> xpad channels-last bf16 ------------------------------
__global__ __launch_bounds__(256) void k_xpad(const float* __restrict__ x,
                                              __bf16* __restrict__ xpad) {
    int pt = blockIdx.x, ct = blockIdx.y, b = blockIdx.z;
    int t = threadIdx.x;
    __shared__ __bf16 lds[64][66];
    int pl = t & 63;
    int cb = t >> 6;
    const float* xb = x + ((size_t)(b * CIN + ct * 64)) * HW + pt * 64;
    #pragma unroll
    for (int ic = 0; ic < 16; ++ic) {
        int cl = ic * 4 + cb;
        lds[cl][pl] = (__bf16)xb[(size_t)cl * HW + pl];
    }
    __syncthreads();
    #pragma unroll
    for (int iw = 0; iw < 2; ++iw) {
        int idx = iw * 256 + t;
        int p_l = idx >> 3, c8 = (idx & 7) * 8;
        int p = pt * 64 + p_l;
        int y = p / WW, xx = p - y * WW;
        union { __bf16 h[8]; uint4 u; } pk;
        #pragma unroll
        for (int j = 0; j < 8; ++j) pk.h[j] = lds[c8 + j][p_l];
        __bf16* dst = xpad + ((size_t)b * XPP + (y + 1) * XP + (xx + 1)) * CIN
                      + ct * 64 + c8;
        *(uint4*)dst = pk.u;
    }
}

// ---------------- implicit-GEMM conv: 256x256 tile, 8-phase, counted vmcnt --
#define GL16(g, l) __builtin_amdgcn_global_load_lds( \
    (const __attribute__((address_space(1))) uint32_t*)(g), \
    (__attribute__((address_space(3))) uint32_t*)(l), 16, 0, 0)

// LDS map (byte offsets within 128KiB dynamic LDS):
//   A slab: buf*32768 + kh*16384          ([256 rows][64B], swizzled)
//   B slab: 65536 + buf*32768 + kh*16384
// swizzle (involution, confined to the 64B row): L ^= ((L>>7)&3)<<4
//   (bits 4-5 only; bit 6 is the row LSB and must NOT be touched)

#define STAGE_A(o, kh, aoffn) do { \
    GL16(gA0 + (aoffn) + (kh)*64, LDS + (o)*32768 + (kh)*16384 + wid*1024); \
    GL16(gA1 + (aoffn) + (kh)*64, LDS + (o)*32768 + (kh)*16384 + 8192 + wid*1024); \
  } while (0)
#define STAGE_B(o, kh, boffn) do { \
    GL16(gB0 + (boffn) + (kh)*64, LDS + 65536 + (o)*32768 + (kh)*16384 + wid*1024); \
    GL16(gB1 + (boffn) + (kh)*64, LDS + 65536 + (o)*32768 + (kh)*16384 + 8192 + wid*1024); \
  } while (0)

#define BARRIER() do { \
    __builtin_amdgcn_sched_barrier(0); \
    __builtin_amdgcn_s_barrier(); \
    __builtin_amdgcn_sched_barrier(0); \
  } while (0)

#define LOADA(aCur, kh, q) do { \
    af[0] = *(const bf16x8*)((aCur) + (kh)*16384 + (q)*4096 + 0); \
    af[1] = *(const bf16x8*)((aCur) + (kh)*16384 + (q)*4096 + 1024); \
    af[2] = *(const bf16x8*)((aCur) + (kh)*16384 + (q)*4096 + 2048); \
    af[3] = *(const bf16x8*)((aCur) + (kh)*16384 + (q)*4096 + 3072); \
  } while (0)
#define LOADB(bCur, kh) do { \
    bq[0] = *(const bf16x8*)((bCur) + (kh)*16384 + 0); \
    bq[1] = *(const bf16x8*)((bCur) + (kh)*16384 + 1024); \
    bq[2] = *(const bf16x8*)((bCur) + (kh)*16384 + 2048); \
    bq[3] = *(const bf16x8*)((bCur) + (kh)*16384 + 3072); \
  } while (0)
#define LGKM0() do { \
    asm volatile("s_waitcnt lgkmcnt(0)" ::: "memory"); \
    __builtin_amdgcn_sched_barrier(0); \
  } while (0)
#define MM(qb) do { \
    __builtin_amdgcn_s_setprio(1); \
    _Pragma("unroll") \
    for (int mf = 0; mf < 4; ++mf) \
      _Pragma("unroll") \
      for (int nf = 0; nf < 4; ++nf) \
        acc[(qb) + mf][nf] = __builtin_amdgcn_mfma_f32_16x16x32_bf16( \
            af[mf], bq[nf], acc[(qb) + mf][nf], 0, 0, 0); \
    __builtin_amdgcn_s_setprio(0); \
  } while (0)

__global__ __launch_bounds__(512, 2) void k_conv(const __bf16* __restrict__ cwt,
                                                 const __bf16* __restrict__ xpad,
                                                 float* __restrict__ out) {
    extern __shared__ __align__(16) char LDS[];

    // XCD swizzle: 416 = 8 * 52 (bijective); 4 consecutive samples per XCD
    int flat = blockIdx.x;
    int logical = (flat & 7) * 52 + (flat >> 3);
    int b  = logical / 13;
    int nt = logical - b * 13;

    int tid = threadIdx.x;
    int ln  = tid & 63;
    int wid = tid >> 6;
    int wr  = wid >> 2;          // 0..1: M-half (rows wr*128..+128)
    int wc  = wid & 3;           // 0..3: N-quarter (cols wc*64..+64)
    int fr  = ln & 15;
    int kw  = ln >> 4;           // 0..3: 16B k-chunk
    int xsw = ((fr >> 1) & 3) << 4;   // 2-bit swizzle, stays inside 64B row

    // ---- per-lane stage source pointers (pre-swizzled global) ----
    const char *gA0, *gA1, *gB0, *gB1;
    {
        const char* cwb = (const char*)(cwt + (size_t)b * COUT * KTOT);
        const char* xpb = (const char*)(xpad + (size_t)b * XPP * CIN);
        #pragma unroll
        for (int i = 0; i < 2; ++i) {
            int L = i * 8192 + wid * 1024 + ln * 16;
            int U = L ^ (((L >> 7) & 3) << 4);   // same involution as reads
            int rowU = U >> 6;           // 0..255
            int kbU  = U & 63;
            const char* ga = cwb + (size_t)rowU * (KTOT * 2) + kbU;
            int p = nt * 256 + rowU; if (p > HW - 1) p = HW - 1;
            int y = p / WW, x = p - y * WW;
            const char* gb = xpb + (size_t)(y * XP + x) * (CIN * 2) + kbU;
            if (i == 0) { gA0 = ga; gB0 = gb; } else { gA1 = ga; gB1 = gb; }
        }
    }

    // ---- per-lane LDS read bases (swizzled) ----
    int aRd = (wr * 128 + fr) * 64 + ((kw * 16) ^ xsw);
    int bRd = (wc * 64 + fr) * 64 + ((kw * 16) ^ xsw);

    f32x4 acc[8][4];
    #pragma unroll
    for (int i = 0; i < 8; ++i)
        #pragma unroll
        for (int j = 0; j < 4; ++j)
            acc[i][j] = (f32x4){0.f, 0.f, 0.f, 0.f};

    bf16x8 af[4], bq[4];

    // ---- prologue: stage K-tile 0 (order Akh0,Bkh0,Akh1,Bkh1) ----
    STAGE_A(0, 0, 0);
    STAGE_B(0, 0, 0);
    STAGE_A(0, 1, 0);
    STAGE_B(0, 1, 0);

    // ---- main loop: kt = 0..34, stage kt+1, counted vmcnt(6) ----
    for (int kt = 0; kt < NKT - 1; ++kt) {
        int c = kt & 1, o = c ^ 1;
        int ktn  = kt + 1;
        int aoffn = ktn * 128;
        int ktap = ktn >> 2;
        int kyn  = (ktap * 11) >> 5;         // ktap/3 for 0..8
        int kxn  = ktap - kyn * 3;
        int boffn = (kyn * XP + kxn) * 512 + (ktn & 3) * 128;
        const char* aCur = LDS + c * 32768 + aRd;
        const char* bCur = LDS + 65536 + c * 32768 + bRd;

        // phase 1: (kh0, q0)
        STAGE_A(o, 0, aoffn);
        asm volatile("s_waitcnt vmcnt(6)" ::: "memory");
        BARRIER();
        LOADA(aCur, 0, 0);
        LOADB(bCur, 0);
        LGKM0();
        MM(0);
        // phase 2: (kh0, q1)
        STAGE_B(o, 0, boffn);
        BARRIER();
        LOADA(aCur, 0, 1);
        LGKM0();
        MM(4);
        // phase 3: (kh1, q0)
        STAGE_A(o, 1, aoffn);
        asm volatile("s_waitcnt vmcnt(6)" ::: "memory");
        BARRIER();
        LOADA(aCur, 1, 0);
        LOADB(bCur, 1);
        LGKM0();
        MM(0);
        // phase 4: (kh1, q1)
        STAGE_B(o, 1, boffn);
        BARRIER();
        LOADA(aCur, 1, 1);
        LGKM0();
        MM(4);
    }

    // ---- tail K-tile 35 (buf 1): drain, no stages ----
    {
        asm volatile("s_waitcnt vmcnt(0)" ::: "memory");
        BARRIER();
        const char* aCur = LDS + 32768 + aRd;
        const char* bCur = LDS + 65536 + 32768 + bRd;
        LOADA(aCur, 0, 0); LOADB(bCur, 0); LGKM0(); MM(0);
        LOADA(aCur, 0, 1);                 LGKM0(); MM(4);
        LOADA(aCur, 1, 0); LOADB(bCur, 1); LGKM0(); MM(0);
        LOADA(aCur, 1, 1);                 LGKM0(); MM(4);
    }

    // ---- epilogue: col = lane&15, row = (lane>>4)*4 + reg ----
    float* ob = out + ((size_t)(b * COUT + wr * 128)) * HW;
    int colbase = nt * 256 + wc * 64;
    int rb = (ln >> 4) * 4;
    #pragma unroll
    for (int q = 0; q < 2; ++q)
        #pragma unroll
        for (int nf = 0; nf < 4; ++nf) {
            int col = colbase + nf * 16 + fr;
            if (col < HW) {
                #pragma unroll
                for (int mf = 0; mf < 4; ++mf)
                    #pragma unroll
                    for (int r = 0; r < 4; ++r)
                        ob[(size_t)(q * 64 + mf * 16 + rb + r) * HW + col] =
                            acc[q * 4 + mf][nf][r];
            }
        }
}

// ---------------------------------------------------------------------------
extern "C" void kernel_launch(void* const* d_in, const int* in_sizes, int n_in,
                              void* d_out, int out_size, void* d_ws, size_t ws_size,
                              hipStream_t stream) {
    (void)in_sizes; (void)n_in; (void)out_size; (void)ws_size;
    const float* x   = (const float*)d_in[0];
    const float* we  = (const float*)d_in[1];
    const float* rcw = (const float*)d_in[2];
    const float* rcb = (const float*)d_in[3];
    const float* fcw = (const float*)d_in[4];
    const float* fcb = (const float*)d_in[5];
    float* out = (float*)d_out;

    char* ws = (char*)d_ws;
    float*  rw     = (float*)(ws + OFF_RW);
    float*  pooled = (float*)(ws + OFF_POOLED);
    __bf16* cwt    = (__bf16*)(ws + OFF_CWT);
    __bf16* xpad   = (__bf16*)(ws + OFF_XPAD);

    // allow 128 KiB dynamic LDS (idempotent; harmless during capture)
    (void)hipFuncSetAttribute((const void*)k_conv,
                              hipFuncAttributeMaxDynamicSharedMemorySize, 131072);

    k_zborder<<<NB, 256, 0, stream>>>(xpad);
    k_pool<<<dim3(NB, CIN), 256, 0, stream>>>(x, pooled);
    k_route<<<NB, 256, 0, stream>>>(pooled, rcw, rcb, fcw, fcb, rw);
    k_mixw<<<COUT, 256, 0, stream>>>(we, rw, cwt);
    k_xpad<<<dim3(49, 4, NB), 256, 0, stream>>>(x, xpad);
    k_conv<<<416, 512, 131072, stream>>>(cwt, xpad, out);
}

// Round 7
// 196.800 us; speedup vs baseline: 1.3835x; 1.0298x over previous
//
#include <hip/hip_runtime.h>
#include <hip/hip_bf16.h>
#include <stdint.h>

#define NB   32
#define CIN  256
#define COUT 256
#define WW   56
#define HW   3136
#define NEXP 3
#define KTOT 2304          // 9 * 256
#define XP   58
#define XPP  3364          // 58*58
#define NKT  36            // K-tiles of 64

typedef __attribute__((ext_vector_type(8))) __bf16 bf16x8;
typedef __attribute__((ext_vector_type(4))) float  f32x4;

// workspace layout (bytes)
#define OFF_RW     0
#define OFF_POOLED 1024
#define OFF_CWT    (1024 + 32*256*16*4)
#define CWT_BYTES  ((size_t)NB*COUT*KTOT*2)
#define OFF_XPAD   (OFF_CWT + CWT_BYTES)

// ---------------- fused prologue: xpad + pool + zborder ---------------------
// blocks [0,6272): xpad   (pt=i%49, ct=(i/49)%4, b=i/196)
// blocks [6272,14464): pool (j=i-6272: b=j>>8, c=j&255)
// blocks [14464,14496): zborder (b = i-14464)
#define PRE_XPAD 6272
#define PRE_POOL 8192
#define PRE_NBLK (PRE_XPAD + PRE_POOL + NB)

__global__ __launch_bounds__(256) void k_pre(const float* __restrict__ x,
                                             float* __restrict__ pooled,
                                             __bf16* __restrict__ xpad) {
    __shared__ __align__(16) char smem[8448];
    int blk = blockIdx.x;
    int t = threadIdx.x;

    if (blk < PRE_XPAD) {
        // ---- xpad: x -> channels-last bf16, padded ----
        int pt = blk % 49;
        int r2 = blk / 49;
        int ct = r2 & 3;
        int b  = r2 >> 2;
        __bf16 (*lds)[66] = (__bf16(*)[66])smem;
        int pl = t & 63;
        int cb = t >> 6;
        const float* xb = x + ((size_t)(b * CIN + ct * 64)) * HW + pt * 64;
        #pragma unroll
        for (int ic = 0; ic < 16; ++ic) {
            int cl = ic * 4 + cb;
            lds[cl][pl] = (__bf16)xb[(size_t)cl * HW + pl];
        }
        __syncthreads();
        #pragma unroll
        for (int iw = 0; iw < 2; ++iw) {
            int idx = iw * 256 + t;
            int p_l = idx >> 3, c8 = (idx & 7) * 8;
            int p = pt * 64 + p_l;
            int y = p / WW, xx = p - y * WW;
            union { __bf16 h[8]; uint4 u; } pk;
            #pragma unroll
            for (int j = 0; j < 8; ++j) pk.h[j] = lds[c8 + j][p_l];
            __bf16* dst = xpad + ((size_t)b * XPP + (y + 1) * XP + (xx + 1)) * CIN
                          + ct * 64 + c8;
            *(uint4*)dst = pk.u;
        }
    } else if (blk < PRE_XPAD + PRE_POOL) {
        // ---- pool: block means 14x14 -> pooled[b,c,16] ----
        int j = blk - PRE_XPAD;
        int b = j >> 8, c = j & 255;
        float (*lds)[56] = (float(*)[56])smem;
        const float* xb = x + ((size_t)(b * CIN + c)) * HW;
        if (t < 224) {
            int xc = t % 56, yg = t / 56;
            const float* p = xb + (yg * 14) * WW + xc;
            float s = 0.f;
            #pragma unroll
            for (int r = 0; r < 14; ++r) s += p[r * WW];
            lds[yg][xc] = s;
        }
        __syncthreads();
        if (t < 16) {
            int sy = t >> 2, sx = t & 3;
            float s = 0.f;
            #pragma unroll
            for (int jj = 0; jj < 14; ++jj) s += lds[sy][sx * 14 + jj];
            pooled[(((size_t)b * CIN + c) << 4) + t] = s * (1.f / 196.f);
        }
    } else {
        // ---- zborder ----
        int b = blk - (PRE_XPAD + PRE_POOL);
        for (int idx = t; idx < 228 * 32; idx += 256) {
            int pos = idx >> 5;
            int co = (idx & 31) * 8;
            int yy, xx;
            if (pos < 58)       { yy = 0;          xx = pos; }
            else if (pos < 116) { yy = 57;         xx = pos - 58; }
            else if (pos < 172) { yy = pos - 115;  xx = 0; }
            else                { yy = pos - 171;  xx = 57; }
            uint4 z = {0u, 0u, 0u, 0u};
            *(uint4*)(xpad + ((size_t)b * XPP + yy * XP + xx) * CIN + co) = z;
        }
    }
}

// ---------------- routing ---------------------------------------------------
__global__ __launch_bounds__(256) void k_route(const float* __restrict__ pooled,
                                               const float* __restrict__ rcw,
                                               const float* __restrict__ rcb,
                                               const float* __restrict__ fcw,
                                               const float* __restrict__ fcb,
                                               float* __restrict__ rw) {
    int b = blockIdx.x;
    int t = threadIdx.x;
    int r = t >> 4, ij = t & 15;
    __shared__ float rbuf[256];
    const float* pb = pooled + (size_t)b * CIN * 16;
    float acc = rcb[r];
    for (int c = 0; c < CIN; ++c)
        acc += pb[c * 16 + ij] * rcw[r * CIN + c];
    rbuf[t] = fmaxf(acc, 0.f);
    __syncthreads();
    if (t < NEXP) {
        float a = fcb[t];
        for (int f = 0; f < 256; ++f) a += rbuf[f] * fcw[t * 256 + f];
        a = fmaxf(a, 0.f);
        rw[b * NEXP + t] = 1.f / (1.f + expf(-a));
    }
}

// ---------------- weight mixing ---------------------------------------------
__global__ __launch_bounds__(256) void k_mixw(const float* __restrict__ we,
                                              const float* __restrict__ rw,
                                              __bf16* __restrict__ cwt) {
    int o = blockIdx.x;
    int i = threadIdx.x;
    float wv[3][9];
    #pragma unroll
    for (int e = 0; e < 3; ++e) {
        const float* p = we + (((size_t)e * COUT + o) * CIN + i) * 9;
        #pragma unroll
        for (int k = 0; k < 9; ++k) wv[e][k] = p[k];
    }
    for (int b = 0; b < NB; ++b) {
        float r0 = rw[b * 3 + 0], r1 = rw[b * 3 + 1], r2 = rw[b * 3 + 2];
        __bf16* op = cwt + ((size_t)(b * COUT + o)) * KTOT + i;
        #pragma unroll
        for (int k = 0; k < 9; ++k) {
            float v = r0 * wv[0][k] + r1 * wv[1][k] + r2 * wv[2][k];
            op[k * 256] = (__bf16)v;
        }
    }
}

// ---------------- implicit-GEMM conv ----------------------------------------
// 256x256 tile, BK=64, 8 waves, 128KiB LDS, 2 barriers + 2 counted vmcnt / K-tile.
//
// vmcnt(4) invariant (per wave, 2 loads per STAGE macro):
//   prologue leaves 8 outstanding (A0,B0,A1,B1 of tile 0).
//   half-0 entry: 8 outstanding -> vmcnt(4) retires the oldest 4 = A0,B0 of
//   the tile about to be read; the following stages re-raise 4->8.
//   half-1 entry: retires A1,B1.  Invariant holds every tile; the peeled
//   tail uses vmcnt(0).
// WAR: each slab's overwrite-issue is >=1 barrier after all waves' last
//   reads of it (reads retire at each wave's own LGKM0 before its MM, and a
//   validation BARRIER separates that MM from the overwriting STAGE).
#define GL16(g, l) __builtin_amdgcn_global_load_lds( \
    (const __attribute__((address_space(1))) uint32_t*)(g), \
    (__attribute__((address_space(3))) uint32_t*)(l), 16, 0, 0)

#define STAGE_A(o, kh, aoffn) do { \
    GL16(gA0 + (aoffn) + (kh)*64, LDS + (o)*32768 + (kh)*16384 + wid*1024); \
    GL16(gA1 + (aoffn) + (kh)*64, LDS + (o)*32768 + (kh)*16384 + 8192 + wid*1024); \
  } while (0)
#define STAGE_B(o, kh, boffn) do { \
    GL16(gB0 + (boffn) + (kh)*64, LDS + 65536 + (o)*32768 + (kh)*16384 + wid*1024); \
    GL16(gB1 + (boffn) + (kh)*64, LDS + 65536 + (o)*32768 + (kh)*16384 + 8192 + wid*1024); \
  } while (0)

#define BARRIER() do { \
    __builtin_amdgcn_sched_barrier(0); \
    __builtin_amdgcn_s_barrier(); \
    __builtin_amdgcn_sched_barrier(0); \
  } while (0)
#define VMCNT(n) do { \
    asm volatile("s_waitcnt vmcnt(" #n ")" ::: "memory"); \
    __builtin_amdgcn_sched_barrier(0); \
  } while (0)

#define LOADA(aCur, kh, q) do { \
    af[0] = *(const bf16x8*)((aCur) + (kh)*16384 + (q)*4096 + 0); \
    af[1] = *(const bf16x8*)((aCur) + (kh)*16384 + (q)*4096 + 1024); \
    af[2] = *(const bf16x8*)((aCur) + (kh)*16384 + (q)*4096 + 2048); \
    af[3] = *(const bf16x8*)((aCur) + (kh)*16384 + (q)*4096 + 3072); \
  } while (0)
#define LOADB(bCur, kh) do { \
    bq[0] = *(const bf16x8*)((bCur) + (kh)*16384 + 0); \
    bq[1] = *(const bf16x8*)((bCur) + (kh)*16384 + 1024); \
    bq[2] = *(const bf16x8*)((bCur) + (kh)*16384 + 2048); \
    bq[3] = *(const bf16x8*)((bCur) + (kh)*16384 + 3072); \
  } while (0)
#define LGKM0() do { \
    asm volatile("s_waitcnt lgkmcnt(0)" ::: "memory"); \
    __builtin_amdgcn_sched_barrier(0); \
  } while (0)
#define MM(qb) do { \
    __builtin_amdgcn_s_setprio(1); \
    _Pragma("unroll") \
    for (int mf = 0; mf < 4; ++mf) \
      _Pragma("unroll") \
      for (int nf = 0; nf < 4; ++nf) \
        acc[(qb) + mf][nf] = __builtin_amdgcn_mfma_f32_16x16x32_bf16( \
            af[mf], bq[nf], acc[(qb) + mf][nf], 0, 0, 0); \
    __builtin_amdgcn_s_setprio(0); \
  } while (0)

__global__ __launch_bounds__(512, 2) void k_conv(const __bf16* __restrict__ cwt,
                                                 const __bf16* __restrict__ xpad,
                                                 float* __restrict__ out) {
    extern __shared__ __align__(16) char LDS[];

    // XCD swizzle: 416 = 8 * 52 (bijective)
    int flat = blockIdx.x;
    int logical = (flat & 7) * 52 + (flat >> 3);
    int b  = logical / 13;
    int nt = logical - b * 13;

    int tid = threadIdx.x;
    int ln  = tid & 63;
    int wid = tid >> 6;
    int wr  = wid >> 2;
    int wc  = wid & 3;
    int fr  = ln & 15;
    int kw  = ln >> 4;
    int xsw = ((fr >> 1) & 3) << 4;   // 2-bit swizzle, inside the 64B row

    const char *gA0, *gA1, *gB0, *gB1;
    {
        const char* cwb = (const char*)(cwt + (size_t)b * COUT * KTOT);
        const char* xpb = (const char*)(xpad + (size_t)b * XPP * CIN);
        #pragma unroll
        for (int i = 0; i < 2; ++i) {
            int L = i * 8192 + wid * 1024 + ln * 16;
            int U = L ^ (((L >> 7) & 3) << 4);   // same involution as reads
            int rowU = U >> 6;
            int kbU  = U & 63;
            const char* ga = cwb + (size_t)rowU * (KTOT * 2) + kbU;
            int p = nt * 256 + rowU; if (p > HW - 1) p = HW - 1;
            int y = p / WW, x = p - y * WW;
            const char* gb = xpb + (size_t)(y * XP + x) * (CIN * 2) + kbU;
            if (i == 0) { gA0 = ga; gB0 = gb; } else { gA1 = ga; gB1 = gb; }
        }
    }

    int aRd = (wr * 128 + fr) * 64 + ((kw * 16) ^ xsw);
    int bRd = (wc * 64 + fr) * 64 + ((kw * 16) ^ xsw);

    f32x4 acc[8][4];
    #pragma unroll
    for (int i = 0; i < 8; ++i)
        #pragma unroll
        for (int j = 0; j < 4; ++j)
            acc[i][j] = (f32x4){0.f, 0.f, 0.f, 0.f};

    bf16x8 af[4], bq[4];

    // prologue: stage K-tile 0 (A0,B0,A1,B1 -> 8 loads outstanding)
    STAGE_A(0, 0, 0);
    STAGE_B(0, 0, 0);
    STAGE_A(0, 1, 0);
    STAGE_B(0, 1, 0);

    for (int kt = 0; kt < NKT - 1; ++kt) {
        int c = kt & 1, o = c ^ 1;
        int ktn  = kt + 1;
        int aoffn = ktn * 128;
        int ktap = ktn >> 2;
        int kyn  = (ktap * 11) >> 5;         // ktap/3 for 0..8
        int kxn  = ktap - kyn * 3;
        int boffn = (kyn * XP + kxn) * 512 + (ktn & 3) * 128;
        const char* aCur = LDS + c * 32768 + aRd;
        const char* bCur = LDS + 65536 + c * 32768 + bRd;

        // ---- half 0: validate A0,B0 then compute kh0 while staging next ----
        VMCNT(4);
        BARRIER();
        LOADA(aCur, 0, 0);
        LOADB(bCur, 0);
        STAGE_A(o, 0, aoffn);
        LGKM0();
        MM(0);
        LOADA(aCur, 0, 1);
        STAGE_B(o, 0, boffn);
        LGKM0();
        MM(4);
        // ---- half 1: validate A1,B1 ----
        VMCNT(4);
        BARRIER();
        LOADA(aCur, 1, 0);
        LOADB(bCur, 1);
        STAGE_A(o, 1, aoffn);
        LGKM0();
        MM(0);
        LOADA(aCur, 1, 1);
        STAGE_B(o, 1, boffn);
        LGKM0();
        MM(4);
    }

    // ---- tail K-tile 35 (buf 1): full drain, no stages ----
    {
        VMCNT(0);
        BARRIER();
        const char* aCur = LDS + 32768 + aRd;
        const char* bCur = LDS + 65536 + 32768 + bRd;
        LOADA(aCur, 0, 0); LOADB(bCur, 0); LGKM0(); MM(0);
        LOADA(aCur, 0, 1);                 LGKM0(); MM(4);
        LOADA(aCur, 1, 0); LOADB(bCur, 1); LGKM0(); MM(0);
        LOADA(aCur, 1, 1);                 LGKM0(); MM(4);
    }

    // ---- epilogue: col = lane&15, row = (lane>>4)*4 + reg ----
    float* ob = out + ((size_t)(b * COUT + wr * 128)) * HW;
    int colbase = nt * 256 + wc * 64;
    int rb = (ln >> 4) * 4;
    #pragma unroll
    for (int q = 0; q < 2; ++q)
        #pragma unroll
        for (int nf = 0; nf < 4; ++nf) {
            int col = colbase + nf * 16 + fr;
            if (col < HW) {
                #pragma unroll
                for (int mf = 0; mf < 4; ++mf)
                    #pragma unroll
                    for (int r = 0; r < 4; ++r)
                        ob[(size_t)(q * 64 + mf * 16 + rb + r) * HW + col] =
                            acc[q * 4 + mf][nf][r];
            }
        }
}

// ---------------------------------------------------------------------------
extern "C" void kernel_launch(void* const* d_in, const int* in_sizes, int n_in,
                              void* d_out, int out_size, void* d_ws, size_t ws_size,
                              hipStream_t stream) {
    (void)in_sizes; (void)n_in; (void)out_size; (void)ws_size;
    const float* x   = (const float*)d_in[0];
    const float* we  = (const float*)d_in[1];
    const float* rcw = (const float*)d_in[2];
    const float* rcb = (const float*)d_in[3];
    const float* fcw = (const float*)d_in[4];
    const float* fcb = (const float*)d_in[5];
    float* out = (float*)d_out;

    char* ws = (char*)d_ws;
    float*  rw     = (float*)(ws + OFF_RW);
    float*  pooled = (float*)(ws + OFF_POOLED);
    __bf16* cwt    = (__bf16*)(ws + OFF_CWT);
    __bf16* xpad   = (__bf16*)(ws + OFF_XPAD);

    (void)hipFuncSetAttribute((const void*)k_conv,
                              hipFuncAttributeMaxDynamicSharedMemorySize, 131072);

    k_pre<<<PRE_NBLK, 256, 0, stream>>>(x, pooled, xpad);
    k_route<<<NB, 256, 0, stream>>>(pooled, rcw, rcb, fcw, fcb, rw);
    k_mixw<<<COUT, 256, 0, stream>>>(we, rw, cwt);
    k_conv<<<416, 512, 131072, stream>>>(cwt, xpad, out);
}